// Round 9
// baseline (293.892 us; speedup 1.0000x reference)
//
#include <hip/hip_runtime.h>
#include <math.h>

// Problem constants
#define Bb 4
#define Ss 4096
#define Dd 1024
#define Hh 16
#define DKk 64
#define Mm (Bb * Ss)          // 16384 rows
#define NCH 16                // n-chunks per head for KV partial reduction

typedef __attribute__((ext_vector_type(8))) short bf16x8;
typedef __attribute__((ext_vector_type(4))) float f32x4;

__device__ __forceinline__ unsigned short f2bf(float f) {
  unsigned u = __float_as_uint(f);
  u += 0x7FFFu + ((u >> 16) & 1u);          // round-to-nearest-even
  return (unsigned short)(u >> 16);
}
__device__ __forceinline__ float bf2f(unsigned short s) {
  return __uint_as_float(((unsigned)s) << 16);
}
__device__ __forceinline__ unsigned cvt2(float lo, float hi) {
  unsigned r;
  asm("v_cvt_pk_bf16_f32 %0, %1, %2" : "=v"(r) : "v"(lo), "v"(hi));
  return r;   // low 16 = bf16(lo), high 16 = bf16(hi), RNE
}

#define GLOAD(dst, src)                                                     \
  __builtin_amdgcn_global_load_lds(                                         \
      (const __attribute__((address_space(1))) void*)(src),                 \
      (__attribute__((address_space(3))) void*)(dst), 16, 0, 0)

// ---------------- fp32 -> bf16: weights (small, 4 tensors) -----------------
__global__ __launch_bounds__(256) void cvt_f32_bf16(
    const float* __restrict__ s0, const float* __restrict__ s1,
    const float* __restrict__ s2, const float* __restrict__ s3,
    unsigned short* __restrict__ d0, unsigned short* __restrict__ d1,
    unsigned short* __restrict__ d2, unsigned short* __restrict__ d3, int n4) {
  const float* s; unsigned short* d;
  switch (blockIdx.y) {
    case 0:  s = s0; d = d0; break;
    case 1:  s = s1; d = d1; break;
    case 2:  s = s2; d = d2; break;
    default: s = s3; d = d3; break;
  }
  const int i = blockIdx.x * 256 + threadIdx.x;
  if (i < n4) {
    float4 v = ((const float4*)s)[i];
    ushort4 o;
    o.x = f2bf(v.x); o.y = f2bf(v.y); o.z = f2bf(v.z); o.w = f2bf(v.w);
    ((ushort4*)d)[i] = o;
  }
}

// ---------------- fp32 -> bf16: activations (grid-stride, 32B/iter) --------
__global__ __launch_bounds__(256) void cvt_pk_f32_bf16(
    const float* __restrict__ s0, const float* __restrict__ s1,
    unsigned short* __restrict__ d0, unsigned short* __restrict__ d1,
    int n8) {
  const float* s = blockIdx.y ? s1 : s0;
  unsigned short* d = blockIdx.y ? d1 : d0;
  for (long i = (long)blockIdx.x * 256 + threadIdx.x; i < n8;
       i += (long)gridDim.x * 256) {
    float4 a = ((const float4*)s)[2 * i];
    float4 b = ((const float4*)s)[2 * i + 1];
    int4 w;
    w.x = cvt2(a.x, a.y); w.y = cvt2(a.z, a.w);
    w.z = cvt2(b.x, b.y); w.w = cvt2(b.z, b.w);
    ((int4*)d)[i] = w;
  }
}

// ---------------- 256x256 8-phase-style bf16 MFMA GEMM ---------------------
// C = act(A[M,1024] @ W[1024,1024]^T + bias). BK=64, 512 thr / 8 waves (2x4).
// Per K-tile: 4 phases = 4 C-quadrants (mh,nh); each phase:
//   12 ds_read_b128 -> [staging gloads] -> [counted vmcnt] -> barrier ->
//   lgkmcnt(0)+sched_barrier -> setprio{16 MFMA} -> barrier.
// LDS rows PERMUTED so each 64-row gload granule = the rows one quadrant
// group needs first: A LDS row = mh*128+wm*64+mi*16+fr (granule l -> global
// row base {0,128,64,192}); B LDS row = nh*128+wn*32+ni*16+fr. Staging of
// tile t+1: first-four loads (Ah0,Bh0) at P1, second-four (Ah1,Bh1) at P2.
// Drains: vmcnt(4)@P1 (frees Ah1/Bh1 of tile t, read at P2/P3/P4),
// vmcnt(4)@P4 (frees Ah0/Bh0 of tile t+1, read at next P1). Never vmcnt(0).
#define LOADQ(mh, nh)                                                        \
  _Pragma("unroll") for (int mi = 0; mi < 4; ++mi)                           \
    _Pragma("unroll") for (int ks = 0; ks < 2; ++ks)                         \
      af[mi][ks] = *(const bf16x8*)(bufA +                                   \
          ((mh) * 128 + wm * 64 + mi * 16 + fr) * 64 + (swz_rd ^ (ks * 32)));\
  _Pragma("unroll") for (int ni = 0; ni < 2; ++ni)                           \
    _Pragma("unroll") for (int ks = 0; ks < 2; ++ks)                         \
      bv_[ni][ks] = *(const bf16x8*)(bufB +                                  \
          ((nh) * 128 + wn * 32 + ni * 16 + fr) * 64 + (swz_rd ^ (ks * 32)));

#define MFMAQ(mh, nh)                                                        \
  __builtin_amdgcn_s_setprio(1);                                             \
  _Pragma("unroll") for (int mi = 0; mi < 4; ++mi)                           \
    _Pragma("unroll") for (int ni = 0; ni < 2; ++ni)                         \
      _Pragma("unroll") for (int ks = 0; ks < 2; ++ks)                       \
        acc[(mh) * 4 + mi][(nh) * 2 + ni] =                                  \
            __builtin_amdgcn_mfma_f32_16x16x32_bf16(                         \
                af[mi][ks], bv_[ni][ks],                                     \
                acc[(mh) * 4 + mi][(nh) * 2 + ni], 0, 0, 0);                 \
  __builtin_amdgcn_s_setprio(0);

#define SYNC_PRE_MFMA()                                                      \
  __builtin_amdgcn_s_barrier();                                              \
  asm volatile("s_waitcnt lgkmcnt(0)" ::: "memory");                         \
  __builtin_amdgcn_sched_barrier(0);

template <typename OutT>
__device__ __forceinline__ void gemm256_body(
    const unsigned short* __restrict__ A,   // [M,1024] bf16 bits
    const unsigned short* __restrict__ W,   // [1024,1024] bf16 bits (N,K)
    const float* __restrict__ bias,
    OutT* __restrict__ C, const int act, const int wg_in,
    unsigned short* lds) {
  const int t = threadIdx.x;
  const int wave = t >> 6, lane = t & 63;
  const int wm = wave >> 2, wn = wave & 3;
  const int fr = lane & 15, fq = lane >> 4;

  // XCD-bijective block swizzle (256 wgs per GEMM, 256 % 8 == 0)
  const int wg = ((wg_in & 7) << 5) | (wg_in >> 3);
  const int bm = wg >> 2, bn = wg & 3;

  f32x4 acc[8][4];
#pragma unroll
  for (int i = 0; i < 8; ++i)
#pragma unroll
    for (int j = 0; j < 4; ++j) acc[i][j] = (f32x4){0.f, 0.f, 0.f, 0.f};

  // staging geometry: load l covers LDS rows [l*64, l*64+64); thread t has
  // LDS row l*64 + (t>>3), LDS col granule (t&7). Global source col is the
  // inverse-swizzled granule; global row per the LDS row permutation.
  const int r = t >> 3;                                  // 0..63
  const int swz_st = ((t & 7) ^ (r & 7)) << 3;           // inverse swizzle
  const unsigned short* gA[4];
  const unsigned short* gB[4];
#pragma unroll
  for (int l = 0; l < 4; ++l) {
    const int ga_row = (l & 1) * 128 + (l >> 1) * 64 + r;   // {0,128,64,192}+r
    const int bb = l * 2 + (r >> 5);
    const int gb_row = (bb & 3) * 64 + (bb >> 2) * 32 + (r & 31);
    gA[l] = A + (size_t)(bm * 256 + ga_row) * Dd + swz_st;
    gB[l] = W + (size_t)(bn * 256 + gb_row) * Dd + swz_st;
  }
  const int dstoff = wave * 512;                         // HW adds lane*16B

  // ds_read geometry (swizzled); LDS row & 7 == fr & 7 for all fragments
  const int swz_rd = (fq * 8) ^ ((fr & 7) << 3);

  // prologue: stage tile 0, halves in drain order [Ah0,Bh0 | Ah1,Bh1]
  GLOAD(lds + 0 * 4096 + dstoff, gA[0]);
  GLOAD(lds + 1 * 4096 + dstoff, gA[1]);
  GLOAD(lds + 16384 + 0 * 4096 + dstoff, gB[0]);
  GLOAD(lds + 16384 + 1 * 4096 + dstoff, gB[1]);
  GLOAD(lds + 2 * 4096 + dstoff, gA[2]);
  GLOAD(lds + 3 * 4096 + dstoff, gA[3]);
  GLOAD(lds + 16384 + 2 * 4096 + dstoff, gB[2]);
  GLOAD(lds + 16384 + 3 * 4096 + dstoff, gB[3]);
  asm volatile("s_waitcnt vmcnt(4)" ::: "memory");   // Ah0,Bh0(0) ready
  __builtin_amdgcn_s_barrier();

  for (int tt = 0; tt < 16; ++tt) {
    unsigned short* bufA = lds + (tt & 1) * 32768;
    unsigned short* bufB = bufA + 16384;
    unsigned short* nA = lds + ((tt & 1) ^ 1) * 32768;
    unsigned short* nB = nA + 16384;
    const int kpre = (tt < 15 ? tt + 1 : 15) * 64;  // clamp: harmless re-stage

    bf16x8 af[4][2], bv_[2][2];
    // ---- P1: quadrant (0,0); issue Ah0,Bh0(t+1); drain Ah1,Bh1(t) ----
    LOADQ(0, 0)
    GLOAD(nA + 0 * 4096 + dstoff, gA[0] + kpre);
    GLOAD(nA + 1 * 4096 + dstoff, gA[1] + kpre);
    GLOAD(nB + 0 * 4096 + dstoff, gB[0] + kpre);
    GLOAD(nB + 1 * 4096 + dstoff, gB[1] + kpre);
    asm volatile("s_waitcnt vmcnt(4)" ::: "memory");
    SYNC_PRE_MFMA()
    MFMAQ(0, 0)
    __builtin_amdgcn_s_barrier();
    // ---- P2: quadrant (0,1); issue Ah1,Bh1(t+1) ----
    LOADQ(0, 1)
    GLOAD(nA + 2 * 4096 + dstoff, gA[2] + kpre);
    GLOAD(nA + 3 * 4096 + dstoff, gA[3] + kpre);
    GLOAD(nB + 2 * 4096 + dstoff, gB[2] + kpre);
    GLOAD(nB + 3 * 4096 + dstoff, gB[3] + kpre);
    SYNC_PRE_MFMA()
    MFMAQ(0, 1)
    __builtin_amdgcn_s_barrier();
    // ---- P3: quadrant (1,0) ----
    LOADQ(1, 0)
    SYNC_PRE_MFMA()
    MFMAQ(1, 0)
    __builtin_amdgcn_s_barrier();
    // ---- P4: quadrant (1,1); drain Ah0,Bh0(t+1) for next P1 ----
    LOADQ(1, 1)
    asm volatile("s_waitcnt vmcnt(4)" ::: "memory");
    SYNC_PRE_MFMA()
    MFMAQ(1, 1)
    __builtin_amdgcn_s_barrier();
  }

  // epilogue: output indexing unchanged by LDS permutation.
  // acc[a][b]: a = mh*4+mi, b = nh*2+ni.
  // row = bm*256 + wm*128 + mh*64 + mi*16 + fq*4 + r
  // col = bn*256 + wn*64 + nh*32 + ni*16 + fr
  const size_t row0 = (size_t)bm * 256 + wm * 128 + fq * 4;
  const int col0 = bn * 256 + wn * 64 + fr;
#pragma unroll
  for (int a = 0; a < 8; ++a) {
    const size_t row_a = row0 + (a >> 2) * 64 + (a & 3) * 16;
#pragma unroll
    for (int b = 0; b < 4; ++b) {
      const int col = col0 + (b >> 1) * 32 + (b & 1) * 16;
      const float bvl = bias[col];
#pragma unroll
      for (int rr2 = 0; rr2 < 4; ++rr2) {
        const size_t row = row_a + rr2;
        float vv = acc[a][b][rr2] + bvl;
        if (act) vv = (vv > 0.f) ? (vv + 1.f) : __expf(vv);   // elu(x)+1
        if constexpr (sizeof(OutT) == 2)
          ((unsigned short*)C)[row * Dd + col] = f2bf(vv);
        else
          ((float*)C)[row * Dd + col] = vv;
      }
    }
  }
}

template <int ACT, typename OutT>
__global__ __launch_bounds__(512, 2) void gemm256(
    const unsigned short* __restrict__ A, const unsigned short* __restrict__ W,
    const float* __restrict__ bias, OutT* __restrict__ C) {
  __shared__ __align__(16) unsigned short lds[2 * 32768];  // 128 KiB
  gemm256_body<OutT>(A, W, bias, C, ACT,
                     blockIdx.x + gridDim.x * blockIdx.y, lds);
}

// k-projection (act=1) and v-projection (act=0) in one launch via z-mux
__global__ __launch_bounds__(512, 2) void gemm256_kv(
    const unsigned short* __restrict__ A0, const unsigned short* __restrict__ W0,
    const float* __restrict__ b0, unsigned short* __restrict__ C0,
    const unsigned short* __restrict__ A1, const unsigned short* __restrict__ W1,
    const float* __restrict__ b1, unsigned short* __restrict__ C1) {
  __shared__ __align__(16) unsigned short lds[2 * 32768];
  const int wg = blockIdx.x + gridDim.x * blockIdx.y;
  if (blockIdx.z == 0)
    gemm256_body<unsigned short>(A0, W0, b0, C0, 1, wg, lds);
  else
    gemm256_body<unsigned short>(A1, W1, b1, C1, 0, wg, lds);
}

// ------------- KV partial: per (b,h,chunk) block, 256 rows ----------------
// part[bx][m*64+d] = sum_n V[n,m]*K[n,d];  part[bx][4096+d] = sum_n K[n,d]
__global__ __launch_bounds__(256) void kv_partial(
    const unsigned short* __restrict__ Kf, const unsigned short* __restrict__ Vf,
    float* __restrict__ part) {
  const int bx = blockIdx.x;            // b*H*NCH + h*NCH + chunk
  const int chunk = bx % NCH;
  const int bh = bx / NCH;
  const int h = bh % Hh, b = bh / Hh;
  const int t = threadIdx.x;
  const int tm = t >> 4, td = t & 15;
  __shared__ float sK[8][64];
  __shared__ float sV[8][64];
  float acc[4][4] = {{0.f}};
  float ksr[4] = {0.f, 0.f, 0.f, 0.f};

  const int which = t >> 7;             // 0: K, 1: V
  const int idx = t & 127;
  const int rr = idx >> 4;              // 0..7
  const int dpos = (idx & 15) << 2;     // 0..60
  const int colbase = h * DKk;
  const int rows = Ss / NCH;            // 256

  for (int n0 = 0; n0 < rows; n0 += 8) {
    const int gr = b * Ss + chunk * rows + n0 + rr;
    const unsigned short* src = which ? Vf : Kf;
    ushort4 raw = *(const ushort4*)&src[(size_t)gr * Dd + colbase + dpos];
    __syncthreads();
    float* dst = which ? &sV[rr][dpos] : &sK[rr][dpos];
    dst[0] = bf2f(raw.x); dst[1] = bf2f(raw.y);
    dst[2] = bf2f(raw.z); dst[3] = bf2f(raw.w);
    __syncthreads();
#pragma unroll
    for (int r = 0; r < 8; ++r) {
      float kv[4], vv[4];
#pragma unroll
      for (int j = 0; j < 4; ++j) kv[j] = sK[r][td * 4 + j];
#pragma unroll
      for (int i = 0; i < 4; ++i) vv[i] = sV[r][tm * 4 + i];
#pragma unroll
      for (int i = 0; i < 4; ++i)
#pragma unroll
        for (int j = 0; j < 4; ++j)
          acc[i][j] = fmaf(vv[i], kv[j], acc[i][j]);
      if (tm == 0) {
#pragma unroll
        for (int j = 0; j < 4; ++j) ksr[j] += kv[j];
      }
    }
  }

  float* p = part + (size_t)bx * 4160;
#pragma unroll
  for (int i = 0; i < 4; ++i)
#pragma unroll
    for (int j = 0; j < 4; ++j)
      p[(tm * 4 + i) * 64 + td * 4 + j] = acc[i][j];
  if (tm == 0) {
#pragma unroll
    for (int j = 0; j < 4; ++j) p[4096 + td * 4 + j] = ksr[j];
  }
}

// ------------- KV reduce: sum NCH partials per head ----------------
__global__ __launch_bounds__(256) void kv_reduce(
    const float* __restrict__ part, float* __restrict__ KV,
    float* __restrict__ Ksum) {
  const int bh = blockIdx.x;
  for (int e = threadIdx.x; e < 4160; e += 256) {
    float s = 0.f;
#pragma unroll
    for (int c = 0; c < NCH; ++c)
      s += part[((size_t)bh * NCH + c) * 4160 + e];
    if (e < 4096) KV[(size_t)bh * 4096 + e] = s;
    else Ksum[bh * 64 + (e - 4096)] = s;
  }
}

// ------------- attention apply via MFMA, in place over Qf (bf16) ----------
__global__ __launch_bounds__(256) void attn_mfma(
    unsigned short* __restrict__ Qf, const float* __restrict__ KV,
    const float* __restrict__ Ksum) {
  const int bh = blockIdx.x;
  const int h = bh & (Hh - 1), b = bh >> 4;
  const int t = threadIdx.x;
  const int wave = t >> 6, lane = t & 63;
  const int fr = lane & 15, fq = lane >> 4;

  bf16x8 bfrag[4][2];
  const float* kvb = KV + (size_t)bh * 4096;
#pragma unroll
  for (int nj = 0; nj < 4; ++nj)
#pragma unroll
    for (int ks = 0; ks < 2; ++ks) {
      const float* src = kvb + (nj * 16 + fr) * 64 + ks * 32 + fq * 8;
      const float4 lo = *(const float4*)src;
      const float4 hi = *(const float4*)(src + 4);
      bf16x8 f;
      f[0] = (short)f2bf(lo.x); f[1] = (short)f2bf(lo.y);
      f[2] = (short)f2bf(lo.z); f[3] = (short)f2bf(lo.w);
      f[4] = (short)f2bf(hi.x); f[5] = (short)f2bf(hi.y);
      f[6] = (short)f2bf(hi.z); f[7] = (short)f2bf(hi.w);
      bfrag[nj][ks] = f;
    }
  bf16x8 zfrag[2];
#pragma unroll
  for (int ks = 0; ks < 2; ++ks) {
    bf16x8 f = (bf16x8){0, 0, 0, 0, 0, 0, 0, 0};
    if (fr == 0) {
      const float* src = Ksum + bh * 64 + ks * 32 + fq * 8;
      const float4 lo = *(const float4*)src;
      const float4 hi = *(const float4*)(src + 4);
      f[0] = (short)f2bf(lo.x); f[1] = (short)f2bf(lo.y);
      f[2] = (short)f2bf(lo.z); f[3] = (short)f2bf(lo.w);
      f[4] = (short)f2bf(hi.x); f[5] = (short)f2bf(hi.y);
      f[6] = (short)f2bf(hi.z); f[7] = (short)f2bf(hi.w);
    }
    zfrag[ks] = f;
  }

  const size_t row0 = (size_t)b * Ss + (size_t)blockIdx.y * 256 + wave * 64;
  unsigned short* qbase = Qf + row0 * Dd + h * DKk;
  bf16x8 afrag[4][2];
#pragma unroll
  for (int mi = 0; mi < 4; ++mi)
#pragma unroll
    for (int ks = 0; ks < 2; ++ks)
      afrag[mi][ks] =
          *(const bf16x8*)(qbase + (size_t)(mi * 16 + fr) * Dd + ks * 32 + fq * 8);

  f32x4 acc[4][4], zacc[4];
#pragma unroll
  for (int mi = 0; mi < 4; ++mi) {
    zacc[mi] = (f32x4){0.f, 0.f, 0.f, 0.f};
#pragma unroll
    for (int nj = 0; nj < 4; ++nj) acc[mi][nj] = (f32x4){0.f, 0.f, 0.f, 0.f};
  }
#pragma unroll
  for (int mi = 0; mi < 4; ++mi)
#pragma unroll
    for (int ks = 0; ks < 2; ++ks) {
      zacc[mi] = __builtin_amdgcn_mfma_f32_16x16x32_bf16(
          afrag[mi][ks], zfrag[ks], zacc[mi], 0, 0, 0);
#pragma unroll
      for (int nj = 0; nj < 4; ++nj)
        acc[mi][nj] = __builtin_amdgcn_mfma_f32_16x16x32_bf16(
            afrag[mi][ks], bfrag[nj][ks], acc[mi][nj], 0, 0, 0);
    }

#pragma unroll
  for (int mi = 0; mi < 4; ++mi)
#pragma unroll
    for (int r = 0; r < 4; ++r) {
      const float zv = __shfl(zacc[mi][r], lane & 48) + 1e-6f;
      const float rz = 1.0f / zv;
      const size_t ro = (size_t)(mi * 16 + fq * 4 + r) * Dd;
#pragma unroll
      for (int nj = 0; nj < 4; ++nj)
        qbase[ro + nj * 16 + fr] = f2bf(acc[mi][nj][r] * rz);
    }
}

// ---------------------------------------------------------------------------
extern "C" void kernel_launch(void* const* d_in, const int* in_sizes, int n_in,
                              void* d_out, int out_size, void* d_ws, size_t ws_size,
                              hipStream_t stream) {
  const float* q  = (const float*)d_in[0];
  const float* k  = (const float*)d_in[1];
  const float* v  = (const float*)d_in[2];
  const float* Wq = (const float*)d_in[3];
  const float* bq = (const float*)d_in[4];
  const float* Wk = (const float*)d_in[5];
  const float* bk = (const float*)d_in[6];
  const float* Wv = (const float*)d_in[7];
  const float* bv = (const float*)d_in[8];
  const float* Wo = (const float*)d_in[9];
  const float* bo = (const float*)d_in[10];
  float* out = (float*)d_out;

  // workspace layout (bf16 stored as ushort)
  unsigned short* kb  = (unsigned short*)d_ws;          // k bf16; later part; later q bf16
  unsigned short* vb  = kb + (size_t)Mm * Dd;           // v bf16
  unsigned short* Kf  = vb + (size_t)Mm * Dd;           // K feats, later Q feats
  unsigned short* Vf  = Kf + (size_t)Mm * Dd;           // V feats
  unsigned short* Wqb = Vf + (size_t)Mm * Dd;
  unsigned short* Wkb = Wqb + (size_t)Dd * Dd;
  unsigned short* Wvb = Wkb + (size_t)Dd * Dd;
  unsigned short* Wob = Wvb + (size_t)Dd * Dd;
  float* KV   = (float*)(Wob + (size_t)Dd * Dd);        // 64*4096 floats
  float* Ksum = KV + (size_t)Bb * Hh * DKk * DKk;       // 4096 floats
  float* part = (float*)kb;                             // 17 MB, lifetime: steps 4-5

  dim3 gg(Dd / 256, Mm / 256);          // (4, 64) = 256 wgs
  dim3 ggkv(Dd / 256, Mm / 256, 2);     // k and v GEMMs fused
  const int n8 = (Mm * Dd) / 8;         // activations: 16M elems -> 2M int4s

  // 1) weights -> bf16
  cvt_f32_bf16<<<dim3(1024, 4), 256, 0, stream>>>(Wq, Wk, Wv, Wo, Wqb, Wkb, Wvb, Wob,
                                                  (Dd * Dd) / 4);
  // 2) k, v -> bf16 (grid-stride)
  cvt_pk_f32_bf16<<<dim3(2048, 2), 256, 0, stream>>>(k, v, kb, vb, n8);
  // 3) K and V projections (one launch)
  gemm256_kv<<<ggkv, 512, 0, stream>>>(kb, Wkb, bk, Kf, vb, Wvb, bv, Vf);
  // 4) KV partial sums (part overwrites kb region; kb dead after step 3)
  kv_partial<<<Bb * Hh * NCH, 256, 0, stream>>>(Kf, Vf, part);
  // 5) reduce
  kv_reduce<<<Bb * Hh, 256, 0, stream>>>(part, KV, Ksum);
  // 6) q -> bf16 (kb region free again after step 5)
  cvt_pk_f32_bf16<<<dim3(2048, 1), 256, 0, stream>>>(q, nullptr, kb, nullptr, n8);
  // 7) Q projection -> Kf (free after step 4)
  gemm256<1, unsigned short><<<gg, 512, 0, stream>>>(kb, Wqb, bq, Kf);
  // 8) attention apply in-place
  attn_mfma<<<dim3(Bb * Hh, Ss / 256), 256, 0, stream>>>(Kf, KV, Ksum);
  // 9) output projection
  gemm256<0, float><<<gg, 512, 0, stream>>>(Kf, Wob, bo, out);
}

// Round 10
// 285.267 us; speedup vs baseline: 1.0302x; 1.0302x over previous
//
#include <hip/hip_runtime.h>
#include <math.h>

// Problem constants
#define Bb 4
#define Ss 4096
#define Dd 1024
#define Hh 16
#define DKk 64
#define Mm (Bb * Ss)          // 16384 rows
#define NCH 16                // n-chunks per head for KV partial reduction

typedef __attribute__((ext_vector_type(8))) short bf16x8;
typedef __attribute__((ext_vector_type(4))) float f32x4;

__device__ __forceinline__ unsigned short f2bf(float f) {
  unsigned u = __float_as_uint(f);
  u += 0x7FFFu + ((u >> 16) & 1u);          // round-to-nearest-even
  return (unsigned short)(u >> 16);
}
__device__ __forceinline__ float bf2f(unsigned short s) {
  return __uint_as_float(((unsigned)s) << 16);
}
__device__ __forceinline__ unsigned cvt2(float lo, float hi) {
  unsigned r;
  asm("v_cvt_pk_bf16_f32 %0, %1, %2" : "=v"(r) : "v"(lo), "v"(hi));
  return r;   // low 16 = bf16(lo), high 16 = bf16(hi), RNE
}

#define GLOAD(dst, src)                                                     \
  __builtin_amdgcn_global_load_lds(                                         \
      (const __attribute__((address_space(1))) void*)(src),                 \
      (__attribute__((address_space(3))) void*)(dst), 16, 0, 0)

// ---------------- fp32 -> bf16: weights (small, 4 tensors) -----------------
__global__ __launch_bounds__(256) void cvt_f32_bf16(
    const float* __restrict__ s0, const float* __restrict__ s1,
    const float* __restrict__ s2, const float* __restrict__ s3,
    unsigned short* __restrict__ d0, unsigned short* __restrict__ d1,
    unsigned short* __restrict__ d2, unsigned short* __restrict__ d3, int n4) {
  const float* s; unsigned short* d;
  switch (blockIdx.y) {
    case 0:  s = s0; d = d0; break;
    case 1:  s = s1; d = d1; break;
    case 2:  s = s2; d = d2; break;
    default: s = s3; d = d3; break;
  }
  const int i = blockIdx.x * 256 + threadIdx.x;
  if (i < n4) {
    float4 v = ((const float4*)s)[i];
    ushort4 o;
    o.x = f2bf(v.x); o.y = f2bf(v.y); o.z = f2bf(v.z); o.w = f2bf(v.w);
    ((ushort4*)d)[i] = o;
  }
}

// ---------------- fp32 -> bf16: activations (grid-stride, 32B/iter) --------
__global__ __launch_bounds__(256) void cvt_pk_f32_bf16(
    const float* __restrict__ s0, const float* __restrict__ s1,
    unsigned short* __restrict__ d0, unsigned short* __restrict__ d1,
    int n8) {
  const float* s = blockIdx.y ? s1 : s0;
  unsigned short* d = blockIdx.y ? d1 : d0;
  for (long i = (long)blockIdx.x * 256 + threadIdx.x; i < n8;
       i += (long)gridDim.x * 256) {
    float4 a = ((const float4*)s)[2 * i];
    float4 b = ((const float4*)s)[2 * i + 1];
    int4 w;
    w.x = cvt2(a.x, a.y); w.y = cvt2(a.z, a.w);
    w.z = cvt2(b.x, b.y); w.w = cvt2(b.z, b.w);
    ((int4*)d)[i] = w;
  }
}

// ---------------- 256x256 phase-pipelined bf16 MFMA GEMM -------------------
// C = act(A[M,1024] @ W[1024,1024]^T + bias). BK=64, 512 thr / 8 waves (2x4).
// 4 phases per K-tile, quadrant order (0,0)->(0,1)->(1,1)->(1,0) with
// REGISTER-CARRIED fragments (each LDS fragment read ONCE, except bv0
// re-read at P4): P1 loads afr(mh=0)+bvr(nh=0) [12 ds_read], P2 loads
// bvr(nh=1) [4], P3 loads afr(mh=1) [8], P4 re-loads bvr(nh=0) [4].
// 28 ds_read_b128/wave/K-tile vs 48 in the naive quadrant scheme.
// LDS rows PERMUTED so each 64-row gload granule = rows one half needs:
// A LDS row = mh*128+wm*64+mi*16+fr; B LDS row = nh*128+wn*32+ni*16+fr.
// Staging of tile t+1: Ah0,Bh0 at P1, Ah1,Bh1 at P2. Drains: vmcnt(4)@P1
// (frees Ah1/Bh1 of t, read at P2/P3), vmcnt(4)@P4 (frees Ah0/Bh0 of t+1,
// read at next P1). Never vmcnt(0) in-loop.
#define LOADA(mh)                                                            \
  _Pragma("unroll") for (int mi = 0; mi < 4; ++mi)                           \
    _Pragma("unroll") for (int ks = 0; ks < 2; ++ks)                         \
      afr[mi][ks] = *(const bf16x8*)(bufA +                                  \
          ((mh) * 128 + wm * 64 + mi * 16 + fr) * 64 + (swz_rd ^ (ks * 32)));

#define LOADB(nh)                                                            \
  _Pragma("unroll") for (int ni = 0; ni < 2; ++ni)                           \
    _Pragma("unroll") for (int ks = 0; ks < 2; ++ks)                         \
      bvr[ni][ks] = *(const bf16x8*)(bufB +                                  \
          ((nh) * 128 + wn * 32 + ni * 16 + fr) * 64 + (swz_rd ^ (ks * 32)));

#define MFMAQ(mh, nh)                                                        \
  __builtin_amdgcn_s_setprio(1);                                             \
  _Pragma("unroll") for (int mi = 0; mi < 4; ++mi)                           \
    _Pragma("unroll") for (int ni = 0; ni < 2; ++ni)                         \
      _Pragma("unroll") for (int ks = 0; ks < 2; ++ks)                       \
        acc[(mh) * 4 + mi][(nh) * 2 + ni] =                                  \
            __builtin_amdgcn_mfma_f32_16x16x32_bf16(                         \
                afr[mi][ks], bvr[ni][ks],                                    \
                acc[(mh) * 4 + mi][(nh) * 2 + ni], 0, 0, 0);                 \
  __builtin_amdgcn_s_setprio(0);

#define SYNC_PRE_MFMA()                                                      \
  __builtin_amdgcn_s_barrier();                                              \
  asm volatile("s_waitcnt lgkmcnt(0)" ::: "memory");                         \
  __builtin_amdgcn_sched_barrier(0);

template <typename OutT>
__device__ __forceinline__ void gemm256_body(
    const unsigned short* __restrict__ A,   // [M,1024] bf16 bits
    const unsigned short* __restrict__ W,   // [1024,1024] bf16 bits (N,K)
    const float* __restrict__ bias,
    OutT* __restrict__ C, const int act, const int wg_in,
    unsigned short* lds) {
  const int t = threadIdx.x;
  const int wave = t >> 6, lane = t & 63;
  const int wm = wave >> 2, wn = wave & 3;
  const int fr = lane & 15, fq = lane >> 4;

  // XCD-bijective block swizzle (256 wgs per GEMM, 256 % 8 == 0)
  const int wg = ((wg_in & 7) << 5) | (wg_in >> 3);
  const int bm = wg >> 2, bn = wg & 3;

  f32x4 acc[8][4];
#pragma unroll
  for (int i = 0; i < 8; ++i)
#pragma unroll
    for (int j = 0; j < 4; ++j) acc[i][j] = (f32x4){0.f, 0.f, 0.f, 0.f};

  // staging geometry: load l covers LDS rows [l*64, l*64+64); thread t has
  // LDS row l*64 + (t>>3), LDS col granule (t&7). Global source col is the
  // inverse-swizzled granule; global row per the LDS row permutation.
  const int r = t >> 3;                                  // 0..63
  const int swz_st = ((t & 7) ^ (r & 7)) << 3;           // inverse swizzle
  const unsigned short* gA[4];
  const unsigned short* gB[4];
#pragma unroll
  for (int l = 0; l < 4; ++l) {
    const int ga_row = (l & 1) * 128 + (l >> 1) * 64 + r;   // {0,128,64,192}+r
    const int bb = l * 2 + (r >> 5);
    const int gb_row = (bb & 3) * 64 + (bb >> 2) * 32 + (r & 31);
    gA[l] = A + (size_t)(bm * 256 + ga_row) * Dd + swz_st;
    gB[l] = W + (size_t)(bn * 256 + gb_row) * Dd + swz_st;
  }
  const int dstoff = wave * 512;                         // HW adds lane*16B

  // ds_read geometry (swizzled); LDS row & 7 == fr & 7 for all fragments
  const int swz_rd = (fq * 8) ^ ((fr & 7) << 3);

  // prologue: stage tile 0, halves in drain order [Ah0,Bh0 | Ah1,Bh1]
  GLOAD(lds + 0 * 4096 + dstoff, gA[0]);
  GLOAD(lds + 1 * 4096 + dstoff, gA[1]);
  GLOAD(lds + 16384 + 0 * 4096 + dstoff, gB[0]);
  GLOAD(lds + 16384 + 1 * 4096 + dstoff, gB[1]);
  GLOAD(lds + 2 * 4096 + dstoff, gA[2]);
  GLOAD(lds + 3 * 4096 + dstoff, gA[3]);
  GLOAD(lds + 16384 + 2 * 4096 + dstoff, gB[2]);
  GLOAD(lds + 16384 + 3 * 4096 + dstoff, gB[3]);
  asm volatile("s_waitcnt vmcnt(4)" ::: "memory");   // Ah0,Bh0(0) ready
  __builtin_amdgcn_s_barrier();

  for (int tt = 0; tt < 16; ++tt) {
    unsigned short* bufA = lds + (tt & 1) * 32768;
    unsigned short* bufB = bufA + 16384;
    unsigned short* nA = lds + ((tt & 1) ^ 1) * 32768;
    unsigned short* nB = nA + 16384;
    const int kpre = (tt < 15 ? tt + 1 : 15) * 64;  // clamp: harmless re-stage

    bf16x8 afr[4][2], bvr[2][2];
    // ---- P1: quadrant (0,0); read afr(0)+bvr(0); issue Ah0,Bh0(t+1);
    //      drain Ah1,Bh1(t) ----
    LOADA(0)
    LOADB(0)
    GLOAD(nA + 0 * 4096 + dstoff, gA[0] + kpre);
    GLOAD(nA + 1 * 4096 + dstoff, gA[1] + kpre);
    GLOAD(nB + 0 * 4096 + dstoff, gB[0] + kpre);
    GLOAD(nB + 1 * 4096 + dstoff, gB[1] + kpre);
    asm volatile("s_waitcnt vmcnt(4)" ::: "memory");
    SYNC_PRE_MFMA()
    MFMAQ(0, 0)
    __builtin_amdgcn_s_barrier();
    // ---- P2: quadrant (0,1); reuse afr(0), read bvr(1); issue Ah1,Bh1 ----
    LOADB(1)
    GLOAD(nA + 2 * 4096 + dstoff, gA[2] + kpre);
    GLOAD(nA + 3 * 4096 + dstoff, gA[3] + kpre);
    GLOAD(nB + 2 * 4096 + dstoff, gB[2] + kpre);
    GLOAD(nB + 3 * 4096 + dstoff, gB[3] + kpre);
    SYNC_PRE_MFMA()
    MFMAQ(0, 1)
    __builtin_amdgcn_s_barrier();
    // ---- P3: quadrant (1,1); read afr(1), reuse bvr(1) ----
    LOADA(1)
    SYNC_PRE_MFMA()
    MFMAQ(1, 1)
    __builtin_amdgcn_s_barrier();
    // ---- P4: quadrant (1,0); reuse afr(1), re-read bvr(0);
    //      drain Ah0,Bh0(t+1) for next P1 ----
    LOADB(0)
    asm volatile("s_waitcnt vmcnt(4)" ::: "memory");
    SYNC_PRE_MFMA()
    MFMAQ(1, 0)
    __builtin_amdgcn_s_barrier();
  }

  // epilogue: output indexing unchanged by LDS permutation.
  // acc[a][b]: a = mh*4+mi, b = nh*2+ni.
  // row = bm*256 + wm*128 + mh*64 + mi*16 + fq*4 + r
  // col = bn*256 + wn*64 + nh*32 + ni*16 + fr
  const size_t row0 = (size_t)bm * 256 + wm * 128 + fq * 4;
  const int col0 = bn * 256 + wn * 64 + fr;
#pragma unroll
  for (int a = 0; a < 8; ++a) {
    const size_t row_a = row0 + (a >> 2) * 64 + (a & 3) * 16;
#pragma unroll
    for (int b = 0; b < 4; ++b) {
      const int col = col0 + (b >> 1) * 32 + (b & 1) * 16;
      const float bvl = bias[col];
#pragma unroll
      for (int rr2 = 0; rr2 < 4; ++rr2) {
        const size_t row = row_a + rr2;
        float vv = acc[a][b][rr2] + bvl;
        if (act) vv = (vv > 0.f) ? (vv + 1.f) : __expf(vv);   // elu(x)+1
        if constexpr (sizeof(OutT) == 2)
          ((unsigned short*)C)[row * Dd + col] = f2bf(vv);
        else
          ((float*)C)[row * Dd + col] = vv;
      }
    }
  }
}

template <int ACT, typename OutT>
__global__ __launch_bounds__(512, 2) void gemm256(
    const unsigned short* __restrict__ A, const unsigned short* __restrict__ W,
    const float* __restrict__ bias, OutT* __restrict__ C) {
  __shared__ __align__(16) unsigned short lds[2 * 32768];  // 128 KiB
  gemm256_body<OutT>(A, W, bias, C, ACT,
                     blockIdx.x + gridDim.x * blockIdx.y, lds);
}

// k-projection (act=1) and v-projection (act=0) in one launch via z-mux
__global__ __launch_bounds__(512, 2) void gemm256_kv(
    const unsigned short* __restrict__ A0, const unsigned short* __restrict__ W0,
    const float* __restrict__ b0, unsigned short* __restrict__ C0,
    const unsigned short* __restrict__ A1, const unsigned short* __restrict__ W1,
    const float* __restrict__ b1, unsigned short* __restrict__ C1) {
  __shared__ __align__(16) unsigned short lds[2 * 32768];
  const int wg = blockIdx.x + gridDim.x * blockIdx.y;
  if (blockIdx.z == 0)
    gemm256_body<unsigned short>(A0, W0, b0, C0, 1, wg, lds);
  else
    gemm256_body<unsigned short>(A1, W1, b1, C1, 0, wg, lds);
}

// ------------- KV partial: per (b,h,chunk) block, 256 rows ----------------
// part[bx][m*64+d] = sum_n V[n,m]*K[n,d];  part[bx][4096+d] = sum_n K[n,d]
__global__ __launch_bounds__(256) void kv_partial(
    const unsigned short* __restrict__ Kf, const unsigned short* __restrict__ Vf,
    float* __restrict__ part) {
  const int bx = blockIdx.x;            // b*H*NCH + h*NCH + chunk
  const int chunk = bx % NCH;
  const int bh = bx / NCH;
  const int h = bh % Hh, b = bh / Hh;
  const int t = threadIdx.x;
  const int tm = t >> 4, td = t & 15;
  __shared__ float sK[8][64];
  __shared__ float sV[8][64];
  float acc[4][4] = {{0.f}};
  float ksr[4] = {0.f, 0.f, 0.f, 0.f};

  const int which = t >> 7;             // 0: K, 1: V
  const int idx = t & 127;
  const int rr = idx >> 4;              // 0..7
  const int dpos = (idx & 15) << 2;     // 0..60
  const int colbase = h * DKk;
  const int rows = Ss / NCH;            // 256

  for (int n0 = 0; n0 < rows; n0 += 8) {
    const int gr = b * Ss + chunk * rows + n0 + rr;
    const unsigned short* src = which ? Vf : Kf;
    ushort4 raw = *(const ushort4*)&src[(size_t)gr * Dd + colbase + dpos];
    __syncthreads();
    float* dst = which ? &sV[rr][dpos] : &sK[rr][dpos];
    dst[0] = bf2f(raw.x); dst[1] = bf2f(raw.y);
    dst[2] = bf2f(raw.z); dst[3] = bf2f(raw.w);
    __syncthreads();
#pragma unroll
    for (int r = 0; r < 8; ++r) {
      float kv[4], vv[4];
#pragma unroll
      for (int j = 0; j < 4; ++j) kv[j] = sK[r][td * 4 + j];
#pragma unroll
      for (int i = 0; i < 4; ++i) vv[i] = sV[r][tm * 4 + i];
#pragma unroll
      for (int i = 0; i < 4; ++i)
#pragma unroll
        for (int j = 0; j < 4; ++j)
          acc[i][j] = fmaf(vv[i], kv[j], acc[i][j]);
      if (tm == 0) {
#pragma unroll
        for (int j = 0; j < 4; ++j) ksr[j] += kv[j];
      }
    }
  }

  float* p = part + (size_t)bx * 4160;
#pragma unroll
  for (int i = 0; i < 4; ++i)
#pragma unroll
    for (int j = 0; j < 4; ++j)
      p[(tm * 4 + i) * 64 + td * 4 + j] = acc[i][j];
  if (tm == 0) {
#pragma unroll
    for (int j = 0; j < 4; ++j) p[4096 + td * 4 + j] = ksr[j];
  }
}

// ------------- KV reduce: sum NCH partials per head ----------------
__global__ __launch_bounds__(256) void kv_reduce(
    const float* __restrict__ part, float* __restrict__ KV,
    float* __restrict__ Ksum) {
  const int bh = blockIdx.x;
  for (int e = threadIdx.x; e < 4160; e += 256) {
    float s = 0.f;
#pragma unroll
    for (int c = 0; c < NCH; ++c)
      s += part[((size_t)bh * NCH + c) * 4160 + e];
    if (e < 4096) KV[(size_t)bh * 4096 + e] = s;
    else Ksum[bh * 64 + (e - 4096)] = s;
  }
}

// ------------- attention apply via MFMA, in place over Qf (bf16) ----------
__global__ __launch_bounds__(256) void attn_mfma(
    unsigned short* __restrict__ Qf, const float* __restrict__ KV,
    const float* __restrict__ Ksum) {
  const int bh = blockIdx.x;
  const int h = bh & (Hh - 1), b = bh >> 4;
  const int t = threadIdx.x;
  const int wave = t >> 6, lane = t & 63;
  const int fr = lane & 15, fq = lane >> 4;

  bf16x8 bfrag[4][2];
  const float* kvb = KV + (size_t)bh * 4096;
#pragma unroll
  for (int nj = 0; nj < 4; ++nj)
#pragma unroll
    for (int ks = 0; ks < 2; ++ks) {
      const float* src = kvb + (nj * 16 + fr) * 64 + ks * 32 + fq * 8;
      const float4 lo = *(const float4*)src;
      const float4 hi = *(const float4*)(src + 4);
      bf16x8 f;
      f[0] = (short)f2bf(lo.x); f[1] = (short)f2bf(lo.y);
      f[2] = (short)f2bf(lo.z); f[3] = (short)f2bf(lo.w);
      f[4] = (short)f2bf(hi.x); f[5] = (short)f2bf(hi.y);
      f[6] = (short)f2bf(hi.z); f[7] = (short)f2bf(hi.w);
      bfrag[nj][ks] = f;
    }
  bf16x8 zfrag[2];
#pragma unroll
  for (int ks = 0; ks < 2; ++ks) {
    bf16x8 f = (bf16x8){0, 0, 0, 0, 0, 0, 0, 0};
    if (fr == 0) {
      const float* src = Ksum + bh * 64 + ks * 32 + fq * 8;
      const float4 lo = *(const float4*)src;
      const float4 hi = *(const float4*)(src + 4);
      f[0] = (short)f2bf(lo.x); f[1] = (short)f2bf(lo.y);
      f[2] = (short)f2bf(lo.z); f[3] = (short)f2bf(lo.w);
      f[4] = (short)f2bf(hi.x); f[5] = (short)f2bf(hi.y);
      f[6] = (short)f2bf(hi.z); f[7] = (short)f2bf(hi.w);
    }
    zfrag[ks] = f;
  }

  const size_t row0 = (size_t)b * Ss + (size_t)blockIdx.y * 256 + wave * 64;
  unsigned short* qbase = Qf + row0 * Dd + h * DKk;
  bf16x8 afrag[4][2];
#pragma unroll
  for (int mi = 0; mi < 4; ++mi)
#pragma unroll
    for (int ks = 0; ks < 2; ++ks)
      afrag[mi][ks] =
          *(const bf16x8*)(qbase + (size_t)(mi * 16 + fr) * Dd + ks * 32 + fq * 8);

  f32x4 acc[4][4], zacc[4];
#pragma unroll
  for (int mi = 0; mi < 4; ++mi) {
    zacc[mi] = (f32x4){0.f, 0.f, 0.f, 0.f};
#pragma unroll
    for (int nj = 0; nj < 4; ++nj) acc[mi][nj] = (f32x4){0.f, 0.f, 0.f, 0.f};
  }
#pragma unroll
  for (int mi = 0; mi < 4; ++mi)
#pragma unroll
    for (int ks = 0; ks < 2; ++ks) {
      zacc[mi] = __builtin_amdgcn_mfma_f32_16x16x32_bf16(
          afrag[mi][ks], zfrag[ks], zacc[mi], 0, 0, 0);
#pragma unroll
      for (int nj = 0; nj < 4; ++nj)
        acc[mi][nj] = __builtin_amdgcn_mfma_f32_16x16x32_bf16(
            afrag[mi][ks], bfrag[nj][ks], acc[mi][nj], 0, 0, 0);
    }

#pragma unroll
  for (int mi = 0; mi < 4; ++mi)
#pragma unroll
    for (int r = 0; r < 4; ++r) {
      const float zv = __shfl(zacc[mi][r], lane & 48) + 1e-6f;
      const float rz = 1.0f / zv;
      const size_t ro = (size_t)(mi * 16 + fq * 4 + r) * Dd;
#pragma unroll
      for (int nj = 0; nj < 4; ++nj)
        qbase[ro + nj * 16 + fr] = f2bf(acc[mi][nj][r] * rz);
    }
}

// ---------------------------------------------------------------------------
extern "C" void kernel_launch(void* const* d_in, const int* in_sizes, int n_in,
                              void* d_out, int out_size, void* d_ws, size_t ws_size,
                              hipStream_t stream) {
  const float* q  = (const float*)d_in[0];
  const float* k  = (const float*)d_in[1];
  const float* v  = (const float*)d_in[2];
  const float* Wq = (const float*)d_in[3];
  const float* bq = (const float*)d_in[4];
  const float* Wk = (const float*)d_in[5];
  const float* bk = (const float*)d_in[6];
  const float* Wv = (const float*)d_in[7];
  const float* bv = (const float*)d_in[8];
  const float* Wo = (const float*)d_in[9];
  const float* bo = (const float*)d_in[10];
  float* out = (float*)d_out;

  // workspace layout (bf16 stored as ushort)
  unsigned short* kb  = (unsigned short*)d_ws;          // k bf16; later part; later q bf16
  unsigned short* vb  = kb + (size_t)Mm * Dd;           // v bf16
  unsigned short* Kf  = vb + (size_t)Mm * Dd;           // K feats, later Q feats
  unsigned short* Vf  = Kf + (size_t)Mm * Dd;           // V feats
  unsigned short* Wqb = Vf + (size_t)Mm * Dd;
  unsigned short* Wkb = Wqb + (size_t)Dd * Dd;
  unsigned short* Wvb = Wkb + (size_t)Dd * Dd;
  unsigned short* Wob = Wvb + (size_t)Dd * Dd;
  float* KV   = (float*)(Wob + (size_t)Dd * Dd);        // 64*4096 floats
  float* Ksum = KV + (size_t)Bb * Hh * DKk * DKk;       // 4096 floats
  float* part = (float*)kb;                             // 17 MB, lifetime: steps 4-5

  dim3 gg(Dd / 256, Mm / 256);          // (4, 64) = 256 wgs
  dim3 ggkv(Dd / 256, Mm / 256, 2);     // k and v GEMMs fused
  const int n8 = (Mm * Dd) / 8;         // activations: 16M elems -> 2M int4s

  // 1) weights -> bf16
  cvt_f32_bf16<<<dim3(1024, 4), 256, 0, stream>>>(Wq, Wk, Wv, Wo, Wqb, Wkb, Wvb, Wob,
                                                  (Dd * Dd) / 4);
  // 2) k, v -> bf16 (grid-stride)
  cvt_pk_f32_bf16<<<dim3(2048, 2), 256, 0, stream>>>(k, v, kb, vb, n8);
  // 3) K and V projections (one launch)
  gemm256_kv<<<ggkv, 512, 0, stream>>>(kb, Wkb, bk, Kf, vb, Wvb, bv, Vf);
  // 4) KV partial sums (part overwrites kb region; kb dead after step 3)
  kv_partial<<<Bb * Hh * NCH, 256, 0, stream>>>(Kf, Vf, part);
  // 5) reduce
  kv_reduce<<<Bb * Hh, 256, 0, stream>>>(part, KV, Ksum);
  // 6) q -> bf16 (kb region free again after step 5)
  cvt_pk_f32_bf16<<<dim3(2048, 1), 256, 0, stream>>>(q, nullptr, kb, nullptr, n8);
  // 7) Q projection -> Kf (free after step 4)
  gemm256<1, unsigned short><<<gg, 512, 0, stream>>>(kb, Wqb, bq, Kf);
  // 8) attention apply in-place
  attn_mfma<<<dim3(Bb * Hh, Ss / 256), 256, 0, stream>>>(Kf, KV, Ksum);
  // 9) output projection
  gemm256<0, float><<<gg, 512, 0, stream>>>(Kf, Wob, bo, out);
}

// Round 11
// 276.267 us; speedup vs baseline: 1.0638x; 1.0326x over previous
//
#include <hip/hip_runtime.h>
#include <math.h>

// Problem constants
#define Bb 4
#define Ss 4096
#define Dd 1024
#define Hh 16
#define DKk 64
#define Mm (Bb * Ss)          // 16384 rows
#define NCH 16                // n-chunks per head for KV partial reduction

typedef __attribute__((ext_vector_type(8))) short bf16x8;
typedef __attribute__((ext_vector_type(4))) float f32x4;

__device__ __forceinline__ unsigned short f2bf(float f) {
  unsigned u = __float_as_uint(f);
  u += 0x7FFFu + ((u >> 16) & 1u);          // round-to-nearest-even
  return (unsigned short)(u >> 16);
}
__device__ __forceinline__ float bf2f(unsigned short s) {
  return __uint_as_float(((unsigned)s) << 16);
}
__device__ __forceinline__ unsigned cvt2(float lo, float hi) {
  unsigned r;
  asm("v_cvt_pk_bf16_f32 %0, %1, %2" : "=v"(r) : "v"(lo), "v"(hi));
  return r;   // low 16 = bf16(lo), high 16 = bf16(hi), RNE
}
__device__ __forceinline__ void cvt8(const float* __restrict__ s,
                                     unsigned short* __restrict__ d, long i) {
  float4 a = ((const float4*)s)[2 * i];
  float4 b = ((const float4*)s)[2 * i + 1];
  int4 w;
  w.x = cvt2(a.x, a.y); w.y = cvt2(a.z, a.w);
  w.z = cvt2(b.x, b.y); w.w = cvt2(b.z, b.w);
  ((int4*)d)[i] = w;
}

#define GLOAD(dst, src)                                                     \
  __builtin_amdgcn_global_load_lds(                                         \
      (const __attribute__((address_space(1))) void*)(src),                 \
      (__attribute__((address_space(3))) void*)(dst), 16, 0, 0)

// ---------------- fp32 -> bf16: k, v, and all four weights, one launch -----
__global__ __launch_bounds__(256) void cvt_all(
    const float* __restrict__ k, const float* __restrict__ v,
    const float* __restrict__ Wq, const float* __restrict__ Wk,
    const float* __restrict__ Wv, const float* __restrict__ Wo,
    unsigned short* __restrict__ kb, unsigned short* __restrict__ vb,
    unsigned short* __restrict__ Wqb, unsigned short* __restrict__ Wkb,
    unsigned short* __restrict__ Wvb, unsigned short* __restrict__ Wob) {
  const int z = blockIdx.z;
  if (z < 2) {
    const float* s = z ? v : k;
    unsigned short* d = z ? vb : kb;
    const long n8 = ((long)Mm * Dd) / 8;
    for (long i = (long)blockIdx.x * 256 + threadIdx.x; i < n8;
         i += (long)gridDim.x * 256)
      cvt8(s, d, i);
  } else {
    const long n8w = ((long)Dd * Dd) / 8;     // 131072 per weight
    for (long i = (long)blockIdx.x * 256 + threadIdx.x; i < 4 * n8w;
         i += (long)gridDim.x * 256) {
      const int which = (int)(i / n8w);
      const long off = i - (long)which * n8w;
      const float* s = (which == 0) ? Wq : (which == 1) ? Wk
                       : (which == 2) ? Wv : Wo;
      unsigned short* d = (which == 0) ? Wqb : (which == 1) ? Wkb
                          : (which == 2) ? Wvb : Wob;
      cvt8(s, d, off);
    }
  }
}

// ---------------- 256x256 phase-pipelined bf16 MFMA GEMM -------------------
// (unchanged from round 10 — register-carried fragments, counted vmcnt,
//  XOR swizzle with pre-swizzled global source, XCD-bijective block swizzle)
#define LOADA(mh)                                                            \
  _Pragma("unroll") for (int mi = 0; mi < 4; ++mi)                           \
    _Pragma("unroll") for (int ks = 0; ks < 2; ++ks)                         \
      afr[mi][ks] = *(const bf16x8*)(bufA +                                  \
          ((mh) * 128 + wm * 64 + mi * 16 + fr) * 64 + (swz_rd ^ (ks * 32)));

#define LOADB(nh)                                                            \
  _Pragma("unroll") for (int ni = 0; ni < 2; ++ni)                           \
    _Pragma("unroll") for (int ks = 0; ks < 2; ++ks)                         \
      bvr[ni][ks] = *(const bf16x8*)(bufB +                                  \
          ((nh) * 128 + wn * 32 + ni * 16 + fr) * 64 + (swz_rd ^ (ks * 32)));

#define MFMAQ(mh, nh)                                                        \
  __builtin_amdgcn_s_setprio(1);                                             \
  _Pragma("unroll") for (int mi = 0; mi < 4; ++mi)                           \
    _Pragma("unroll") for (int ni = 0; ni < 2; ++ni)                         \
      _Pragma("unroll") for (int ks = 0; ks < 2; ++ks)                       \
        acc[(mh) * 4 + mi][(nh) * 2 + ni] =                                  \
            __builtin_amdgcn_mfma_f32_16x16x32_bf16(                         \
                afr[mi][ks], bvr[ni][ks],                                    \
                acc[(mh) * 4 + mi][(nh) * 2 + ni], 0, 0, 0);                 \
  __builtin_amdgcn_s_setprio(0);

#define SYNC_PRE_MFMA()                                                      \
  __builtin_amdgcn_s_barrier();                                              \
  asm volatile("s_waitcnt lgkmcnt(0)" ::: "memory");                         \
  __builtin_amdgcn_sched_barrier(0);

template <typename OutT>
__device__ __forceinline__ void gemm256_body(
    const unsigned short* __restrict__ A,   // [M,1024] bf16 bits
    const unsigned short* __restrict__ W,   // [1024,1024] bf16 bits (N,K)
    const float* __restrict__ bias,
    OutT* __restrict__ C, const int act, const int wg_in,
    unsigned short* lds) {
  const int t = threadIdx.x;
  const int wave = t >> 6, lane = t & 63;
  const int wm = wave >> 2, wn = wave & 3;
  const int fr = lane & 15, fq = lane >> 4;

  // XCD-bijective block swizzle (256 wgs per GEMM, 256 % 8 == 0)
  const int wg = ((wg_in & 7) << 5) | (wg_in >> 3);
  const int bm = wg >> 2, bn = wg & 3;

  f32x4 acc[8][4];
#pragma unroll
  for (int i = 0; i < 8; ++i)
#pragma unroll
    for (int j = 0; j < 4; ++j) acc[i][j] = (f32x4){0.f, 0.f, 0.f, 0.f};

  const int r = t >> 3;                                  // 0..63
  const int swz_st = ((t & 7) ^ (r & 7)) << 3;           // inverse swizzle
  const unsigned short* gA[4];
  const unsigned short* gB[4];
#pragma unroll
  for (int l = 0; l < 4; ++l) {
    const int ga_row = (l & 1) * 128 + (l >> 1) * 64 + r;   // {0,128,64,192}+r
    const int bb = l * 2 + (r >> 5);
    const int gb_row = (bb & 3) * 64 + (bb >> 2) * 32 + (r & 31);
    gA[l] = A + (size_t)(bm * 256 + ga_row) * Dd + swz_st;
    gB[l] = W + (size_t)(bn * 256 + gb_row) * Dd + swz_st;
  }
  const int dstoff = wave * 512;                         // HW adds lane*16B

  const int swz_rd = (fq * 8) ^ ((fr & 7) << 3);

  // prologue: stage tile 0, halves in drain order [Ah0,Bh0 | Ah1,Bh1]
  GLOAD(lds + 0 * 4096 + dstoff, gA[0]);
  GLOAD(lds + 1 * 4096 + dstoff, gA[1]);
  GLOAD(lds + 16384 + 0 * 4096 + dstoff, gB[0]);
  GLOAD(lds + 16384 + 1 * 4096 + dstoff, gB[1]);
  GLOAD(lds + 2 * 4096 + dstoff, gA[2]);
  GLOAD(lds + 3 * 4096 + dstoff, gA[3]);
  GLOAD(lds + 16384 + 2 * 4096 + dstoff, gB[2]);
  GLOAD(lds + 16384 + 3 * 4096 + dstoff, gB[3]);
  asm volatile("s_waitcnt vmcnt(4)" ::: "memory");   // Ah0,Bh0(0) ready
  __builtin_amdgcn_s_barrier();

  for (int tt = 0; tt < 16; ++tt) {
    unsigned short* bufA = lds + (tt & 1) * 32768;
    unsigned short* bufB = bufA + 16384;
    unsigned short* nA = lds + ((tt & 1) ^ 1) * 32768;
    unsigned short* nB = nA + 16384;
    const int kpre = (tt < 15 ? tt + 1 : 15) * 64;  // clamp: harmless re-stage

    bf16x8 afr[4][2], bvr[2][2];
    // ---- P1: (0,0); read afr(0)+bvr(0); issue Ah0,Bh0(t+1); drain t's h1 ----
    LOADA(0)
    LOADB(0)
    GLOAD(nA + 0 * 4096 + dstoff, gA[0] + kpre);
    GLOAD(nA + 1 * 4096 + dstoff, gA[1] + kpre);
    GLOAD(nB + 0 * 4096 + dstoff, gB[0] + kpre);
    GLOAD(nB + 1 * 4096 + dstoff, gB[1] + kpre);
    asm volatile("s_waitcnt vmcnt(4)" ::: "memory");
    SYNC_PRE_MFMA()
    MFMAQ(0, 0)
    __builtin_amdgcn_s_barrier();
    // ---- P2: (0,1); reuse afr(0), read bvr(1); issue Ah1,Bh1(t+1) ----
    LOADB(1)
    GLOAD(nA + 2 * 4096 + dstoff, gA[2] + kpre);
    GLOAD(nA + 3 * 4096 + dstoff, gA[3] + kpre);
    GLOAD(nB + 2 * 4096 + dstoff, gB[2] + kpre);
    GLOAD(nB + 3 * 4096 + dstoff, gB[3] + kpre);
    SYNC_PRE_MFMA()
    MFMAQ(0, 1)
    __builtin_amdgcn_s_barrier();
    // ---- P3: (1,1); read afr(1), reuse bvr(1) ----
    LOADA(1)
    SYNC_PRE_MFMA()
    MFMAQ(1, 1)
    __builtin_amdgcn_s_barrier();
    // ---- P4: (1,0); reuse afr(1), re-read bvr(0); drain Ah0,Bh0(t+1) ----
    LOADB(0)
    asm volatile("s_waitcnt vmcnt(4)" ::: "memory");
    SYNC_PRE_MFMA()
    MFMAQ(1, 0)
    __builtin_amdgcn_s_barrier();
  }

  // epilogue: acc[a][b]: a = mh*4+mi, b = nh*2+ni.
  const size_t row0 = (size_t)bm * 256 + wm * 128 + fq * 4;
  const int col0 = bn * 256 + wn * 64 + fr;
#pragma unroll
  for (int a = 0; a < 8; ++a) {
    const size_t row_a = row0 + (a >> 2) * 64 + (a & 3) * 16;
#pragma unroll
    for (int b = 0; b < 4; ++b) {
      const int col = col0 + (b >> 1) * 32 + (b & 1) * 16;
      const float bvl = bias[col];
#pragma unroll
      for (int rr2 = 0; rr2 < 4; ++rr2) {
        const size_t row = row_a + rr2;
        float vv = acc[a][b][rr2] + bvl;
        if (act) vv = (vv > 0.f) ? (vv + 1.f) : __expf(vv);   // elu(x)+1
        if constexpr (sizeof(OutT) == 2)
          ((unsigned short*)C)[row * Dd + col] = f2bf(vv);
        else
          ((float*)C)[row * Dd + col] = vv;
      }
    }
  }
}

template <int ACT, typename OutT>
__global__ __launch_bounds__(512, 2) void gemm256(
    const unsigned short* __restrict__ A, const unsigned short* __restrict__ W,
    const float* __restrict__ bias, OutT* __restrict__ C) {
  __shared__ __align__(16) unsigned short lds[2 * 32768];  // 128 KiB
  gemm256_body<OutT>(A, W, bias, C, ACT,
                     blockIdx.x + gridDim.x * blockIdx.y, lds);
}

// k-projection (act=1) and v-projection (act=0) in one launch via z-mux
__global__ __launch_bounds__(512, 2) void gemm256_kv(
    const unsigned short* __restrict__ A0, const unsigned short* __restrict__ W0,
    const float* __restrict__ b0, unsigned short* __restrict__ C0,
    const unsigned short* __restrict__ A1, const unsigned short* __restrict__ W1,
    const float* __restrict__ b1, unsigned short* __restrict__ C1) {
  __shared__ __align__(16) unsigned short lds[2 * 32768];
  const int wg = blockIdx.x + gridDim.x * blockIdx.y;
  if (blockIdx.z == 0)
    gemm256_body<unsigned short>(A0, W0, b0, C0, 1, wg, lds);
  else
    gemm256_body<unsigned short>(A1, W1, b1, C1, 0, wg, lds);
}

// Q-projection GEMM (z=0) + kv_reduce (z=1, 64 active blocks) in one launch
__global__ __launch_bounds__(512, 2) void gemm256_qred(
    const unsigned short* __restrict__ A, const unsigned short* __restrict__ W,
    const float* __restrict__ bias, unsigned short* __restrict__ C,
    const float* __restrict__ part, float* __restrict__ KV,
    float* __restrict__ Ksum) {
  __shared__ __align__(16) unsigned short lds[2 * 32768];
  const int wg = blockIdx.x + gridDim.x * blockIdx.y;
  if (blockIdx.z == 0) {
    gemm256_body<unsigned short>(A, W, bias, C, 1, wg, lds);
  } else {
    const int bh = wg;
    if (bh >= Bb * Hh || threadIdx.x >= 256) return;
    for (int e = threadIdx.x; e < 4160; e += 256) {
      float s = 0.f;
#pragma unroll
      for (int c = 0; c < NCH; ++c)
        s += part[((size_t)bh * NCH + c) * 4160 + e];
      if (e < 4096) KV[(size_t)bh * 4096 + e] = s;
      else Ksum[bh * 64 + (e - 4096)] = s;
    }
  }
}

// ------------- KV partial (y=0, 1024 blocks) + q cvt (y=1) ----------------
// part[bx][m*64+d] = sum_n V[n,m]*K[n,d];  part[bx][4096+d] = sum_n K[n,d]
__global__ __launch_bounds__(256) void kvp_cvtq(
    const unsigned short* __restrict__ Kf, const unsigned short* __restrict__ Vf,
    float* __restrict__ part,
    const float* __restrict__ q, unsigned short* __restrict__ qb) {
  if (blockIdx.y == 1) {
    const long n8 = ((long)Mm * Dd) / 8;
    for (long i = (long)blockIdx.x * 256 + threadIdx.x; i < n8;
         i += (long)gridDim.x * 256)
      cvt8(q, qb, i);
    return;
  }
  const int bx = blockIdx.x;            // b*H*NCH + h*NCH + chunk
  if (bx >= Bb * Hh * NCH) return;
  const int chunk = bx % NCH;
  const int bh = bx / NCH;
  const int h = bh % Hh, b = bh / Hh;
  const int t = threadIdx.x;
  const int tm = t >> 4, td = t & 15;
  __shared__ float sK[8][64];
  __shared__ float sV[8][64];
  float acc[4][4] = {{0.f}};
  float ksr[4] = {0.f, 0.f, 0.f, 0.f};

  const int which = t >> 7;             // 0: K, 1: V
  const int idx = t & 127;
  const int rr = idx >> 4;              // 0..7
  const int dpos = (idx & 15) << 2;     // 0..60
  const int colbase = h * DKk;
  const int rows = Ss / NCH;            // 256

  for (int n0 = 0; n0 < rows; n0 += 8) {
    const int gr = b * Ss + chunk * rows + n0 + rr;
    const unsigned short* src = which ? Vf : Kf;
    ushort4 raw = *(const ushort4*)&src[(size_t)gr * Dd + colbase + dpos];
    __syncthreads();
    float* dst = which ? &sV[rr][dpos] : &sK[rr][dpos];
    dst[0] = bf2f(raw.x); dst[1] = bf2f(raw.y);
    dst[2] = bf2f(raw.z); dst[3] = bf2f(raw.w);
    __syncthreads();
#pragma unroll
    for (int r = 0; r < 8; ++r) {
      float kv[4], vv[4];
#pragma unroll
      for (int j = 0; j < 4; ++j) kv[j] = sK[r][td * 4 + j];
#pragma unroll
      for (int i = 0; i < 4; ++i) vv[i] = sV[r][tm * 4 + i];
#pragma unroll
      for (int i = 0; i < 4; ++i)
#pragma unroll
        for (int j = 0; j < 4; ++j)
          acc[i][j] = fmaf(vv[i], kv[j], acc[i][j]);
      if (tm == 0) {
#pragma unroll
        for (int j = 0; j < 4; ++j) ksr[j] += kv[j];
      }
    }
  }

  float* p = part + (size_t)bx * 4160;
#pragma unroll
  for (int i = 0; i < 4; ++i)
#pragma unroll
    for (int j = 0; j < 4; ++j)
      p[(tm * 4 + i) * 64 + td * 4 + j] = acc[i][j];
  if (tm == 0) {
#pragma unroll
    for (int j = 0; j < 4; ++j) p[4096 + td * 4 + j] = ksr[j];
  }
}

// ------------- attention apply via MFMA, in place over Qf (bf16) ----------
__global__ __launch_bounds__(256) void attn_mfma(
    unsigned short* __restrict__ Qf, const float* __restrict__ KV,
    const float* __restrict__ Ksum) {
  const int bh = blockIdx.x;
  const int h = bh & (Hh - 1), b = bh >> 4;
  const int t = threadIdx.x;
  const int wave = t >> 6, lane = t & 63;
  const int fr = lane & 15, fq = lane >> 4;

  bf16x8 bfrag[4][2];
  const float* kvb = KV + (size_t)bh * 4096;
#pragma unroll
  for (int nj = 0; nj < 4; ++nj)
#pragma unroll
    for (int ks = 0; ks < 2; ++ks) {
      const float* src = kvb + (nj * 16 + fr) * 64 + ks * 32 + fq * 8;
      const float4 lo = *(const float4*)src;
      const float4 hi = *(const float4*)(src + 4);
      bf16x8 f;
      f[0] = (short)f2bf(lo.x); f[1] = (short)f2bf(lo.y);
      f[2] = (short)f2bf(lo.z); f[3] = (short)f2bf(lo.w);
      f[4] = (short)f2bf(hi.x); f[5] = (short)f2bf(hi.y);
      f[6] = (short)f2bf(hi.z); f[7] = (short)f2bf(hi.w);
      bfrag[nj][ks] = f;
    }
  bf16x8 zfrag[2];
#pragma unroll
  for (int ks = 0; ks < 2; ++ks) {
    bf16x8 f = (bf16x8){0, 0, 0, 0, 0, 0, 0, 0};
    if (fr == 0) {
      const float* src = Ksum + bh * 64 + ks * 32 + fq * 8;
      const float4 lo = *(const float4*)src;
      const float4 hi = *(const float4*)(src + 4);
      f[0] = (short)f2bf(lo.x); f[1] = (short)f2bf(lo.y);
      f[2] = (short)f2bf(lo.z); f[3] = (short)f2bf(lo.w);
      f[4] = (short)f2bf(hi.x); f[5] = (short)f2bf(hi.y);
      f[6] = (short)f2bf(hi.z); f[7] = (short)f2bf(hi.w);
    }
    zfrag[ks] = f;
  }

  const size_t row0 = (size_t)b * Ss + (size_t)blockIdx.y * 256 + wave * 64;
  unsigned short* qbase = Qf + row0 * Dd + h * DKk;
  bf16x8 afrag[4][2];
#pragma unroll
  for (int mi = 0; mi < 4; ++mi)
#pragma unroll
    for (int ks = 0; ks < 2; ++ks)
      afrag[mi][ks] =
          *(const bf16x8*)(qbase + (size_t)(mi * 16 + fr) * Dd + ks * 32 + fq * 8);

  f32x4 acc[4][4], zacc[4];
#pragma unroll
  for (int mi = 0; mi < 4; ++mi) {
    zacc[mi] = (f32x4){0.f, 0.f, 0.f, 0.f};
#pragma unroll
    for (int nj = 0; nj < 4; ++nj) acc[mi][nj] = (f32x4){0.f, 0.f, 0.f, 0.f};
  }
#pragma unroll
  for (int mi = 0; mi < 4; ++mi)
#pragma unroll
    for (int ks = 0; ks < 2; ++ks) {
      zacc[mi] = __builtin_amdgcn_mfma_f32_16x16x32_bf16(
          afrag[mi][ks], zfrag[ks], zacc[mi], 0, 0, 0);
#pragma unroll
      for (int nj = 0; nj < 4; ++nj)
        acc[mi][nj] = __builtin_amdgcn_mfma_f32_16x16x32_bf16(
            afrag[mi][ks], bfrag[nj][ks], acc[mi][nj], 0, 0, 0);
    }

#pragma unroll
  for (int mi = 0; mi < 4; ++mi)
#pragma unroll
    for (int r = 0; r < 4; ++r) {
      const float zv = __shfl(zacc[mi][r], lane & 48) + 1e-6f;
      const float rz = 1.0f / zv;
      const size_t ro = (size_t)(mi * 16 + fq * 4 + r) * Dd;
#pragma unroll
      for (int nj = 0; nj < 4; ++nj)
        qbase[ro + nj * 16 + fr] = f2bf(acc[mi][nj][r] * rz);
    }
}

// ---------------------------------------------------------------------------
extern "C" void kernel_launch(void* const* d_in, const int* in_sizes, int n_in,
                              void* d_out, int out_size, void* d_ws, size_t ws_size,
                              hipStream_t stream) {
  const float* q  = (const float*)d_in[0];
  const float* k  = (const float*)d_in[1];
  const float* v  = (const float*)d_in[2];
  const float* Wq = (const float*)d_in[3];
  const float* bq = (const float*)d_in[4];
  const float* Wk = (const float*)d_in[5];
  const float* bk = (const float*)d_in[6];
  const float* Wv = (const float*)d_in[7];
  const float* bv = (const float*)d_in[8];
  const float* Wo = (const float*)d_in[9];
  const float* bo = (const float*)d_in[10];
  float* out = (float*)d_out;

  // workspace layout (bf16 stored as ushort)
  unsigned short* kb  = (unsigned short*)d_ws;          // k bf16; later q bf16
  unsigned short* vb  = kb + (size_t)Mm * Dd;           // v bf16; later part fp32
  unsigned short* Kf  = vb + (size_t)Mm * Dd;           // K feats, later Q feats
  unsigned short* Vf  = Kf + (size_t)Mm * Dd;           // V feats
  unsigned short* Wqb = Vf + (size_t)Mm * Dd;
  unsigned short* Wkb = Wqb + (size_t)Dd * Dd;
  unsigned short* Wvb = Wkb + (size_t)Dd * Dd;
  unsigned short* Wob = Wvb + (size_t)Dd * Dd;
  float* KV   = (float*)(Wob + (size_t)Dd * Dd);        // 64*4096 floats
  float* Ksum = KV + (size_t)Bb * Hh * DKk * DKk;       // 4096 floats
  float* part = (float*)vb;                             // 17 MB, steps 3-4

  dim3 gg(Dd / 256, Mm / 256);          // (4, 64) = 256 wgs
  dim3 ggz(Dd / 256, Mm / 256, 2);      // +z
  const int b0 = 0;

  // 1) k, v, weights -> bf16 (one launch)
  cvt_all<<<dim3(2048, 1, 3), 256, 0, stream>>>(k, v, Wq, Wk, Wv, Wo,
                                                kb, vb, Wqb, Wkb, Wvb, Wob);
  // 2) K and V projections (one launch)
  gemm256_kv<<<ggz, 512, 0, stream>>>(kb, Wkb, bk, Kf, vb, Wvb, bv, Vf);
  // 3) KV partial sums (part -> vb region) + q cvt (-> kb region), one launch
  kvp_cvtq<<<dim3(2048, 2), 256, 0, stream>>>(Kf, Vf, part, q, kb);
  // 4) Q projection (kb -> Kf) + kv_reduce (part -> KV, Ksum), one launch
  gemm256_qred<<<ggz, 512, 0, stream>>>(kb, Wqb, bq, Kf, part, KV, Ksum);
  // 5) attention apply in-place on Qf(=Kf)
  attn_mfma<<<dim3(Bb * Hh, Ss / 256), 256, 0, stream>>>(Kf, KV, Ksum);
  // 6) output projection
  gemm256<0, float><<<gg, 512, 0, stream>>>(Kf, Wob, bo, out);
  (void)b0; (void)in_sizes; (void)n_in; (void)out_size; (void)ws_size;
}

// Round 12
// 262.554 us; speedup vs baseline: 1.1194x; 1.0522x over previous
//
#include <hip/hip_runtime.h>
#include <math.h>

// Problem constants
#define Bb 4
#define Ss 4096
#define Dd 1024
#define Hh 16
#define DKk 64
#define Mm (Bb * Ss)          // 16384 rows
#define NCH 16                // n-chunks per head for KV partial reduction

typedef __attribute__((ext_vector_type(8))) short bf16x8;
typedef __attribute__((ext_vector_type(4))) float f32x4;

__device__ __forceinline__ unsigned short f2bf(float f) {
  unsigned u = __float_as_uint(f);
  u += 0x7FFFu + ((u >> 16) & 1u);          // round-to-nearest-even
  return (unsigned short)(u >> 16);
}
__device__ __forceinline__ float bf2f(unsigned short s) {
  return __uint_as_float(((unsigned)s) << 16);
}
__device__ __forceinline__ unsigned cvt2(float lo, float hi) {
  unsigned r;
  asm("v_cvt_pk_bf16_f32 %0, %1, %2" : "=v"(r) : "v"(lo), "v"(hi));
  return r;   // low 16 = bf16(lo), high 16 = bf16(hi), RNE
}
__device__ __forceinline__ void cvt8(const float* __restrict__ s,
                                     unsigned short* __restrict__ d, long i) {
  float4 a = ((const float4*)s)[2 * i];
  float4 b = ((const float4*)s)[2 * i + 1];
  int4 w;
  w.x = cvt2(a.x, a.y); w.y = cvt2(a.z, a.w);
  w.z = cvt2(b.x, b.y); w.w = cvt2(b.z, b.w);
  ((int4*)d)[i] = w;
}

#define GLOAD(dst, src)                                                     \
  __builtin_amdgcn_global_load_lds(                                         \
      (const __attribute__((address_space(1))) void*)(src),                 \
      (__attribute__((address_space(3))) void*)(dst), 16, 0, 0)

// ---------------- fp32 -> bf16: k, v, and all four weights, one launch -----
__global__ __launch_bounds__(256) void cvt_all(
    const float* __restrict__ k, const float* __restrict__ v,
    const float* __restrict__ Wq, const float* __restrict__ Wk,
    const float* __restrict__ Wv, const float* __restrict__ Wo,
    unsigned short* __restrict__ kb, unsigned short* __restrict__ vb,
    unsigned short* __restrict__ Wqb, unsigned short* __restrict__ Wkb,
    unsigned short* __restrict__ Wvb, unsigned short* __restrict__ Wob) {
  const int z = blockIdx.z;
  if (z < 2) {
    const float* s = z ? v : k;
    unsigned short* d = z ? vb : kb;
    const long n8 = ((long)Mm * Dd) / 8;
    for (long i = (long)blockIdx.x * 256 + threadIdx.x; i < n8;
         i += (long)gridDim.x * 256)
      cvt8(s, d, i);
  } else {
    const long n8w = ((long)Dd * Dd) / 8;     // 131072 per weight
    for (long i = (long)blockIdx.x * 256 + threadIdx.x; i < 4 * n8w;
         i += (long)gridDim.x * 256) {
      const int which = (int)(i / n8w);
      const long off = i - (long)which * n8w;
      const float* s = (which == 0) ? Wq : (which == 1) ? Wk
                       : (which == 2) ? Wv : Wo;
      unsigned short* d = (which == 0) ? Wqb : (which == 1) ? Wkb
                          : (which == 2) ? Wvb : Wob;
      cvt8(s, d, off);
    }
  }
}

// ---------------- 256x256 phase-pipelined bf16 MFMA GEMM -------------------
// Round-11 change: 2 barriers per K-tile (was 8). Within a tile all phases
// only READ buf(t); gloads write the other buffer -> no intra-tile LDS
// hazard. Required barriers: (1) after P1's vmcnt(4) [publish tile-t h1 to
// other waves], (2) tile boundary after P4 [all buf(t) reads done (each
// wave's own lgkmcnt(0) precedes arrival) + publish h0(t+1)]. Per-phase
// lgkmcnt(0) is per-wave (own ds_reads) -> no barrier. Waves free-run
// within the tile so one wave's MFMA hides another's ds_read latency.
#define LOADA(mh)                                                            \
  _Pragma("unroll") for (int mi = 0; mi < 4; ++mi)                           \
    _Pragma("unroll") for (int ks = 0; ks < 2; ++ks)                         \
      afr[mi][ks] = *(const bf16x8*)(bufA +                                  \
          ((mh) * 128 + wm * 64 + mi * 16 + fr) * 64 + (swz_rd ^ (ks * 32)));

#define LOADB(nh)                                                            \
  _Pragma("unroll") for (int ni = 0; ni < 2; ++ni)                           \
    _Pragma("unroll") for (int ks = 0; ks < 2; ++ks)                         \
      bvr[ni][ks] = *(const bf16x8*)(bufB +                                  \
          ((nh) * 128 + wn * 32 + ni * 16 + fr) * 64 + (swz_rd ^ (ks * 32)));

#define MFMAQ(mh, nh)                                                        \
  __builtin_amdgcn_s_setprio(1);                                             \
  _Pragma("unroll") for (int mi = 0; mi < 4; ++mi)                           \
    _Pragma("unroll") for (int ni = 0; ni < 2; ++ni)                         \
      _Pragma("unroll") for (int ks = 0; ks < 2; ++ks)                       \
        acc[(mh) * 4 + mi][(nh) * 2 + ni] =                                  \
            __builtin_amdgcn_mfma_f32_16x16x32_bf16(                         \
                afr[mi][ks], bvr[ni][ks],                                    \
                acc[(mh) * 4 + mi][(nh) * 2 + ni], 0, 0, 0);                 \
  __builtin_amdgcn_s_setprio(0);

// per-wave fence: wait own ds_reads, pin order (rule #18)
#define LGKM_FENCE()                                                         \
  asm volatile("s_waitcnt lgkmcnt(0)" ::: "memory");                         \
  __builtin_amdgcn_sched_barrier(0);

template <typename OutT>
__device__ __forceinline__ void gemm256_body(
    const unsigned short* __restrict__ A,   // [M,1024] bf16 bits
    const unsigned short* __restrict__ W,   // [1024,1024] bf16 bits (N,K)
    const float* __restrict__ bias,
    OutT* __restrict__ C, const int act, const int wg_in,
    unsigned short* lds) {
  const int t = threadIdx.x;
  const int wave = t >> 6, lane = t & 63;
  const int wm = wave >> 2, wn = wave & 3;
  const int fr = lane & 15, fq = lane >> 4;

  // XCD-bijective block swizzle (256 wgs per GEMM, 256 % 8 == 0)
  const int wg = ((wg_in & 7) << 5) | (wg_in >> 3);
  const int bm = wg >> 2, bn = wg & 3;

  f32x4 acc[8][4];
#pragma unroll
  for (int i = 0; i < 8; ++i)
#pragma unroll
    for (int j = 0; j < 4; ++j) acc[i][j] = (f32x4){0.f, 0.f, 0.f, 0.f};

  const int r = t >> 3;                                  // 0..63
  const int swz_st = ((t & 7) ^ (r & 7)) << 3;           // inverse swizzle
  const unsigned short* gA[4];
  const unsigned short* gB[4];
#pragma unroll
  for (int l = 0; l < 4; ++l) {
    const int ga_row = (l & 1) * 128 + (l >> 1) * 64 + r;   // {0,128,64,192}+r
    const int bb = l * 2 + (r >> 5);
    const int gb_row = (bb & 3) * 64 + (bb >> 2) * 32 + (r & 31);
    gA[l] = A + (size_t)(bm * 256 + ga_row) * Dd + swz_st;
    gB[l] = W + (size_t)(bn * 256 + gb_row) * Dd + swz_st;
  }
  const int dstoff = wave * 512;                         // HW adds lane*16B

  const int swz_rd = (fq * 8) ^ ((fr & 7) << 3);

  // prologue: stage tile 0, halves in drain order [Ah0,Bh0 | Ah1,Bh1]
  GLOAD(lds + 0 * 4096 + dstoff, gA[0]);
  GLOAD(lds + 1 * 4096 + dstoff, gA[1]);
  GLOAD(lds + 16384 + 0 * 4096 + dstoff, gB[0]);
  GLOAD(lds + 16384 + 1 * 4096 + dstoff, gB[1]);
  GLOAD(lds + 2 * 4096 + dstoff, gA[2]);
  GLOAD(lds + 3 * 4096 + dstoff, gA[3]);
  GLOAD(lds + 16384 + 2 * 4096 + dstoff, gB[2]);
  GLOAD(lds + 16384 + 3 * 4096 + dstoff, gB[3]);
  asm volatile("s_waitcnt vmcnt(4)" ::: "memory");   // Ah0,Bh0(0) ready
  __builtin_amdgcn_s_barrier();

  for (int tt = 0; tt < 16; ++tt) {
    unsigned short* bufA = lds + (tt & 1) * 32768;
    unsigned short* bufB = bufA + 16384;
    unsigned short* nA = lds + ((tt & 1) ^ 1) * 32768;
    unsigned short* nB = nA + 16384;
    const int kpre = (tt < 15 ? tt + 1 : 15) * 64;  // clamp: harmless re-stage

    bf16x8 afr[4][2], bvr[2][2];
    // ---- P1: (0,0); read afr(0)+bvr(0) [h0]; issue Ah0,Bh0(t+1);
    //      drain h1(t); barrier publishes h1(t) ----
    LOADA(0)
    LOADB(0)
    GLOAD(nA + 0 * 4096 + dstoff, gA[0] + kpre);
    GLOAD(nA + 1 * 4096 + dstoff, gA[1] + kpre);
    GLOAD(nB + 0 * 4096 + dstoff, gB[0] + kpre);
    GLOAD(nB + 1 * 4096 + dstoff, gB[1] + kpre);
    asm volatile("s_waitcnt vmcnt(4)" ::: "memory");
    __builtin_amdgcn_s_barrier();
    LGKM_FENCE()
    MFMAQ(0, 0)
    // ---- P2: (0,1); reuse afr(0), read bvr(1) [h1]; issue Ah1,Bh1(t+1) ----
    LOADB(1)
    GLOAD(nA + 2 * 4096 + dstoff, gA[2] + kpre);
    GLOAD(nA + 3 * 4096 + dstoff, gA[3] + kpre);
    GLOAD(nB + 2 * 4096 + dstoff, gB[2] + kpre);
    GLOAD(nB + 3 * 4096 + dstoff, gB[3] + kpre);
    LGKM_FENCE()
    MFMAQ(0, 1)
    // ---- P3: (1,1); read afr(1) [h1], reuse bvr(1) ----
    LOADA(1)
    LGKM_FENCE()
    MFMAQ(1, 1)
    // ---- P4: (1,0); reuse afr(1), re-read bvr(0) [h0]; drain h0(t+1);
    //      tile-boundary barrier ----
    LOADB(0)
    asm volatile("s_waitcnt vmcnt(4)" ::: "memory");
    LGKM_FENCE()
    MFMAQ(1, 0)
    __builtin_amdgcn_s_barrier();
  }

  // epilogue: acc[a][b]: a = mh*4+mi, b = nh*2+ni.
  const size_t row0 = (size_t)bm * 256 + wm * 128 + fq * 4;
  const int col0 = bn * 256 + wn * 64 + fr;
#pragma unroll
  for (int a = 0; a < 8; ++a) {
    const size_t row_a = row0 + (a >> 2) * 64 + (a & 3) * 16;
#pragma unroll
    for (int b = 0; b < 4; ++b) {
      const int col = col0 + (b >> 1) * 32 + (b & 1) * 16;
      const float bvl = bias[col];
#pragma unroll
      for (int rr2 = 0; rr2 < 4; ++rr2) {
        const size_t row = row_a + rr2;
        float vv = acc[a][b][rr2] + bvl;
        if (act) vv = (vv > 0.f) ? (vv + 1.f) : __expf(vv);   // elu(x)+1
        if constexpr (sizeof(OutT) == 2)
          ((unsigned short*)C)[row * Dd + col] = f2bf(vv);
        else
          ((float*)C)[row * Dd + col] = vv;
      }
    }
  }
}

template <int ACT, typename OutT>
__global__ __launch_bounds__(512, 2) void gemm256(
    const unsigned short* __restrict__ A, const unsigned short* __restrict__ W,
    const float* __restrict__ bias, OutT* __restrict__ C) {
  __shared__ __align__(16) unsigned short lds[2 * 32768];  // 128 KiB
  gemm256_body<OutT>(A, W, bias, C, ACT,
                     blockIdx.x + gridDim.x * blockIdx.y, lds);
}

// k-projection (act=1) and v-projection (act=0) in one launch via z-mux
__global__ __launch_bounds__(512, 2) void gemm256_kv(
    const unsigned short* __restrict__ A0, const unsigned short* __restrict__ W0,
    const float* __restrict__ b0, unsigned short* __restrict__ C0,
    const unsigned short* __restrict__ A1, const unsigned short* __restrict__ W1,
    const float* __restrict__ b1, unsigned short* __restrict__ C1) {
  __shared__ __align__(16) unsigned short lds[2 * 32768];
  const int wg = blockIdx.x + gridDim.x * blockIdx.y;
  if (blockIdx.z == 0)
    gemm256_body<unsigned short>(A0, W0, b0, C0, 1, wg, lds);
  else
    gemm256_body<unsigned short>(A1, W1, b1, C1, 0, wg, lds);
}

// Q-projection GEMM (z=0) + kv_reduce (z=1, 64 active blocks) in one launch
__global__ __launch_bounds__(512, 2) void gemm256_qred(
    const unsigned short* __restrict__ A, const unsigned short* __restrict__ W,
    const float* __restrict__ bias, unsigned short* __restrict__ C,
    const float* __restrict__ part, float* __restrict__ KV,
    float* __restrict__ Ksum) {
  __shared__ __align__(16) unsigned short lds[2 * 32768];
  const int wg = blockIdx.x + gridDim.x * blockIdx.y;
  if (blockIdx.z == 0) {
    gemm256_body<unsigned short>(A, W, bias, C, 1, wg, lds);
  } else {
    const int bh = wg;
    if (bh >= Bb * Hh || threadIdx.x >= 256) return;
    for (int e = threadIdx.x; e < 4160; e += 256) {
      float s = 0.f;
#pragma unroll
      for (int c = 0; c < NCH; ++c)
        s += part[((size_t)bh * NCH + c) * 4160 + e];
      if (e < 4096) KV[(size_t)bh * 4096 + e] = s;
      else Ksum[bh * 64 + (e - 4096)] = s;
    }
  }
}

// ------------- KV partial (y=0, 1024 blocks) + q cvt (y=1) ----------------
// part[bx][m*64+d] = sum_n V[n,m]*K[n,d];  part[bx][4096+d] = sum_n K[n,d]
__global__ __launch_bounds__(256) void kvp_cvtq(
    const unsigned short* __restrict__ Kf, const unsigned short* __restrict__ Vf,
    float* __restrict__ part,
    const float* __restrict__ q, unsigned short* __restrict__ qb) {
  if (blockIdx.y == 1) {
    const long n8 = ((long)Mm * Dd) / 8;
    for (long i = (long)blockIdx.x * 256 + threadIdx.x; i < n8;
         i += (long)gridDim.x * 256)
      cvt8(q, qb, i);
    return;
  }
  const int bx = blockIdx.x;            // b*H*NCH + h*NCH + chunk
  if (bx >= Bb * Hh * NCH) return;
  const int chunk = bx % NCH;
  const int bh = bx / NCH;
  const int h = bh % Hh, b = bh / Hh;
  const int t = threadIdx.x;
  const int tm = t >> 4, td = t & 15;
  __shared__ float sK[8][64];
  __shared__ float sV[8][64];
  float acc[4][4] = {{0.f}};
  float ksr[4] = {0.f, 0.f, 0.f, 0.f};

  const int which = t >> 7;             // 0: K, 1: V
  const int idx = t & 127;
  const int rr = idx >> 4;              // 0..7
  const int dpos = (idx & 15) << 2;     // 0..60
  const int colbase = h * DKk;
  const int rows = Ss / NCH;            // 256

  for (int n0 = 0; n0 < rows; n0 += 8) {
    const int gr = b * Ss + chunk * rows + n0 + rr;
    const unsigned short* src = which ? Vf : Kf;
    ushort4 raw = *(const ushort4*)&src[(size_t)gr * Dd + colbase + dpos];
    __syncthreads();
    float* dst = which ? &sV[rr][dpos] : &sK[rr][dpos];
    dst[0] = bf2f(raw.x); dst[1] = bf2f(raw.y);
    dst[2] = bf2f(raw.z); dst[3] = bf2f(raw.w);
    __syncthreads();
#pragma unroll
    for (int r = 0; r < 8; ++r) {
      float kv[4], vv[4];
#pragma unroll
      for (int j = 0; j < 4; ++j) kv[j] = sK[r][td * 4 + j];
#pragma unroll
      for (int i = 0; i < 4; ++i) vv[i] = sV[r][tm * 4 + i];
#pragma unroll
      for (int i = 0; i < 4; ++i)
#pragma unroll
        for (int j = 0; j < 4; ++j)
          acc[i][j] = fmaf(vv[i], kv[j], acc[i][j]);
      if (tm == 0) {
#pragma unroll
        for (int j = 0; j < 4; ++j) ksr[j] += kv[j];
      }
    }
  }

  float* p = part + (size_t)bx * 4160;
#pragma unroll
  for (int i = 0; i < 4; ++i)
#pragma unroll
    for (int j = 0; j < 4; ++j)
      p[(tm * 4 + i) * 64 + td * 4 + j] = acc[i][j];
  if (tm == 0) {
#pragma unroll
    for (int j = 0; j < 4; ++j) p[4096 + td * 4 + j] = ksr[j];
  }
}

// ------------- attention apply via MFMA, in place over Qf (bf16) ----------
__global__ __launch_bounds__(256) void attn_mfma(
    unsigned short* __restrict__ Qf, const float* __restrict__ KV,
    const float* __restrict__ Ksum) {
  const int bh = blockIdx.x;
  const int h = bh & (Hh - 1), b = bh >> 4;
  const int t = threadIdx.x;
  const int wave = t >> 6, lane = t & 63;
  const int fr = lane & 15, fq = lane >> 4;

  bf16x8 bfrag[4][2];
  const float* kvb = KV + (size_t)bh * 4096;
#pragma unroll
  for (int nj = 0; nj < 4; ++nj)
#pragma unroll
    for (int ks = 0; ks < 2; ++ks) {
      const float* src = kvb + (nj * 16 + fr) * 64 + ks * 32 + fq * 8;
      const float4 lo = *(const float4*)src;
      const float4 hi = *(const float4*)(src + 4);
      bf16x8 f;
      f[0] = (short)f2bf(lo.x); f[1] = (short)f2bf(lo.y);
      f[2] = (short)f2bf(lo.z); f[3] = (short)f2bf(lo.w);
      f[4] = (short)f2bf(hi.x); f[5] = (short)f2bf(hi.y);
      f[6] = (short)f2bf(hi.z); f[7] = (short)f2bf(hi.w);
      bfrag[nj][ks] = f;
    }
  bf16x8 zfrag[2];
#pragma unroll
  for (int ks = 0; ks < 2; ++ks) {
    bf16x8 f = (bf16x8){0, 0, 0, 0, 0, 0, 0, 0};
    if (fr == 0) {
      const float* src = Ksum + bh * 64 + ks * 32 + fq * 8;
      const float4 lo = *(const float4*)src;
      const float4 hi = *(const float4*)(src + 4);
      f[0] = (short)f2bf(lo.x); f[1] = (short)f2bf(lo.y);
      f[2] = (short)f2bf(lo.z); f[3] = (short)f2bf(lo.w);
      f[4] = (short)f2bf(hi.x); f[5] = (short)f2bf(hi.y);
      f[6] = (short)f2bf(hi.z); f[7] = (short)f2bf(hi.w);
    }
    zfrag[ks] = f;
  }

  const size_t row0 = (size_t)b * Ss + (size_t)blockIdx.y * 256 + wave * 64;
  unsigned short* qbase = Qf + row0 * Dd + h * DKk;
  bf16x8 afrag[4][2];
#pragma unroll
  for (int mi = 0; mi < 4; ++mi)
#pragma unroll
    for (int ks = 0; ks < 2; ++ks)
      afrag[mi][ks] =
          *(const bf16x8*)(qbase + (size_t)(mi * 16 + fr) * Dd + ks * 32 + fq * 8);

  f32x4 acc[4][4], zacc[4];
#pragma unroll
  for (int mi = 0; mi < 4; ++mi) {
    zacc[mi] = (f32x4){0.f, 0.f, 0.f, 0.f};
#pragma unroll
    for (int nj = 0; nj < 4; ++nj) acc[mi][nj] = (f32x4){0.f, 0.f, 0.f, 0.f};
  }
#pragma unroll
  for (int mi = 0; mi < 4; ++mi)
#pragma unroll
    for (int ks = 0; ks < 2; ++ks) {
      zacc[mi] = __builtin_amdgcn_mfma_f32_16x16x32_bf16(
          afrag[mi][ks], zfrag[ks], zacc[mi], 0, 0, 0);
#pragma unroll
      for (int nj = 0; nj < 4; ++nj)
        acc[mi][nj] = __builtin_amdgcn_mfma_f32_16x16x32_bf16(
            afrag[mi][ks], bfrag[nj][ks], acc[mi][nj], 0, 0, 0);
    }

#pragma unroll
  for (int mi = 0; mi < 4; ++mi)
#pragma unroll
    for (int r = 0; r < 4; ++r) {
      const float zv = __shfl(zacc[mi][r], lane & 48) + 1e-6f;
      const float rz = 1.0f / zv;
      const size_t ro = (size_t)(mi * 16 + fq * 4 + r) * Dd;
#pragma unroll
      for (int nj = 0; nj < 4; ++nj)
        qbase[ro + nj * 16 + fr] = f2bf(acc[mi][nj][r] * rz);
    }
}

// ---------------------------------------------------------------------------
extern "C" void kernel_launch(void* const* d_in, const int* in_sizes, int n_in,
                              void* d_out, int out_size, void* d_ws, size_t ws_size,
                              hipStream_t stream) {
  const float* q  = (const float*)d_in[0];
  const float* k  = (const float*)d_in[1];
  const float* v  = (const float*)d_in[2];
  const float* Wq = (const float*)d_in[3];
  const float* bq = (const float*)d_in[4];
  const float* Wk = (const float*)d_in[5];
  const float* bk = (const float*)d_in[6];
  const float* Wv = (const float*)d_in[7];
  const float* bv = (const float*)d_in[8];
  const float* Wo = (const float*)d_in[9];
  const float* bo = (const float*)d_in[10];
  float* out = (float*)d_out;

  // workspace layout (bf16 stored as ushort)
  unsigned short* kb  = (unsigned short*)d_ws;          // k bf16; later q bf16
  unsigned short* vb  = kb + (size_t)Mm * Dd;           // v bf16; later part fp32
  unsigned short* Kf  = vb + (size_t)Mm * Dd;           // K feats, later Q feats
  unsigned short* Vf  = Kf + (size_t)Mm * Dd;           // V feats
  unsigned short* Wqb = Vf + (size_t)Mm * Dd;
  unsigned short* Wkb = Wqb + (size_t)Dd * Dd;
  unsigned short* Wvb = Wkb + (size_t)Dd * Dd;
  unsigned short* Wob = Wvb + (size_t)Dd * Dd;
  float* KV   = (float*)(Wob + (size_t)Dd * Dd);        // 64*4096 floats
  float* Ksum = KV + (size_t)Bb * Hh * DKk * DKk;       // 4096 floats
  float* part = (float*)vb;                             // 17 MB, steps 3-4

  dim3 gg(Dd / 256, Mm / 256);          // (4, 64) = 256 wgs
  dim3 ggz(Dd / 256, Mm / 256, 2);      // +z

  // 1) k, v, weights -> bf16 (one launch)
  cvt_all<<<dim3(2048, 1, 3), 256, 0, stream>>>(k, v, Wq, Wk, Wv, Wo,
                                                kb, vb, Wqb, Wkb, Wvb, Wob);
  // 2) K and V projections (one launch)
  gemm256_kv<<<ggz, 512, 0, stream>>>(kb, Wkb, bk, Kf, vb, Wvb, bv, Vf);
  // 3) KV partial sums (part -> vb region) + q cvt (-> kb region), one launch
  kvp_cvtq<<<dim3(2048, 2), 256, 0, stream>>>(Kf, Vf, part, q, kb);
  // 4) Q projection (kb -> Kf) + kv_reduce (part -> KV, Ksum), one launch
  gemm256_qred<<<ggz, 512, 0, stream>>>(kb, Wqb, bq, Kf, part, KV, Ksum);
  // 5) attention apply in-place on Qf(=Kf)
  attn_mfma<<<dim3(Bb * Hh, Ss / 256), 256, 0, stream>>>(Kf, KV, Ksum);
  // 6) output projection
  gemm256<0, float><<<gg, 512, 0, stream>>>(Kf, Wob, bo, out);
  (void)in_sizes; (void)n_in; (void)out_size; (void)ws_size;
}